// Round 2
// baseline (738.303 us; speedup 1.0000x reference)
//
#include <hip/hip_runtime.h>

// Problem constants (must match reference)
#define B_DIM 16
#define S_DIM 512
#define N_HASH 8
#define M_BLOOM 4096
#define W_WIN 2
#define K_BLOCKS (2 * W_WIN + 1)                       // 5
#define OUT_ELEMS (B_DIM * K_BLOCKS * M_BLOOM * S_DIM) // 167,772,160 floats

// Clang native vector type — __builtin_nontemporal_store rejects HIP's
// float4 class type but accepts ext_vector_type.
typedef float fx4 __attribute__((ext_vector_type(4)));

// Kernel 1: dense zero-fill of the output (poisoned to 0xAA before each call).
// Pure streaming writes; 16 B/lane nontemporal stores.
__global__ void zero_out_kernel(fx4* __restrict__ out, int n4) {
    const fx4 z = {0.0f, 0.0f, 0.0f, 0.0f};
    int idx = blockIdx.x * blockDim.x + threadIdx.x;
    const int stride = gridDim.x * blockDim.x;
    for (int i = idx; i < n4; i += stride) {
        __builtin_nontemporal_store(z, out + i);
    }
}

// Kernel 2: scatter. One thread per (b, s, n) hash. Each hash contributes
// +1 to out[b, k*M + m, s + (W-k)] for k = 0..4 (clipped on s).
// Total atomics: 16*512*8*5 = 327,680 — negligible vs the 671 MB fill.
__global__ void scatter_kernel(const int* __restrict__ hashes,
                               float* __restrict__ out) {
    int idx = blockIdx.x * blockDim.x + threadIdx.x;
    if (idx >= B_DIM * S_DIM * N_HASH) return;

    // hashes layout [B, S, N]: idx = (b*S + s)*N + n
    const int b = idx / (S_DIM * N_HASH);
    const int s = (idx / N_HASH) % S_DIM;

    const int h = hashes[idx];
    const int m = h & (M_BLOOM - 1);  // == remainder(h, 4096), h >= 0

    // out flat index: ((b*5 + k)*M + m)*S + s_out
    const long long base_bm = ((long long)b * K_BLOCKS) * M_BLOOM + m;
#pragma unroll
    for (int k = 0; k < K_BLOCKS; ++k) {
        const int s_out = s + (W_WIN - k);
        if (s_out >= 0 && s_out < S_DIM) {
            const long long off =
                (base_bm + (long long)k * M_BLOOM) * S_DIM + s_out;
            atomicAdd(out + off, 1.0f);
        }
    }
}

extern "C" void kernel_launch(void* const* d_in, const int* in_sizes, int n_in,
                              void* d_out, int out_size, void* d_ws, size_t ws_size,
                              hipStream_t stream) {
    const int* hashes = (const int*)d_in[0];
    float* out = (float*)d_out;

    // 1) zero-fill: 167,772,160 floats = 41,943,040 16B stores.
    const int n4 = OUT_ELEMS / 4;
    zero_out_kernel<<<8192, 256, 0, stream>>>((fx4*)out, n4);

    // 2) scatter: one thread per hash (65,536 threads).
    const int total_hashes = B_DIM * S_DIM * N_HASH;
    scatter_kernel<<<(total_hashes + 255) / 256, 256, 0, stream>>>(hashes, out);
}

// Round 3
// 706.254 us; speedup vs baseline: 1.0454x; 1.0454x over previous
//
#include <hip/hip_runtime.h>

// Problem constants (must match reference)
#define B_DIM 16
#define S_DIM 512
#define N_HASH 8
#define M_BLOOM 4096
#define W_WIN 2
#define K_BLOCKS (2 * W_WIN + 1)                       // 5
#define OUT_ELEMS (B_DIM * K_BLOCKS * M_BLOOM * S_DIM) // 167,772,160 floats

typedef float fx4 __attribute__((ext_vector_type(4)));

// Kernel 1: dense zero-fill of the output (poisoned to 0xAA before each call).
// Plain cached 16 B/lane stores — nontemporal (nt) stores measured ~6x slower
// on gfx950 (R2: 738 us total vs 110 us write-roofline; rocclr fill hits
// 6.1 TB/s with regular stores).
__global__ void zero_out_kernel(fx4* __restrict__ out, int n4) {
    const fx4 z = {0.0f, 0.0f, 0.0f, 0.0f};
    int idx = blockIdx.x * blockDim.x + threadIdx.x;
    const int stride = gridDim.x * blockDim.x;
    for (int i = idx; i < n4; i += stride) {
        out[i] = z;
    }
}

// Kernel 2: scatter. One thread per (b, s, n) hash. Each hash contributes
// +1 to out[b, k*M + m, s + (W-k)] for k = 0..4 (clipped on s).
// Total atomics: 16*512*8*5 = 327,680 — negligible vs the 671 MB fill.
__global__ void scatter_kernel(const int* __restrict__ hashes,
                               float* __restrict__ out) {
    int idx = blockIdx.x * blockDim.x + threadIdx.x;
    if (idx >= B_DIM * S_DIM * N_HASH) return;

    // hashes layout [B, S, N]: idx = (b*S + s)*N + n
    const int b = idx / (S_DIM * N_HASH);
    const int s = (idx / N_HASH) % S_DIM;

    const int h = hashes[idx];
    const int m = h & (M_BLOOM - 1);  // == remainder(h, 4096), h >= 0

    // out flat index: ((b*5 + k)*M + m)*S + s_out
    const long long base_bm = ((long long)b * K_BLOCKS) * M_BLOOM + m;
#pragma unroll
    for (int k = 0; k < K_BLOCKS; ++k) {
        const int s_out = s + (W_WIN - k);
        if (s_out >= 0 && s_out < S_DIM) {
            const long long off =
                (base_bm + (long long)k * M_BLOOM) * S_DIM + s_out;
            atomicAdd(out + off, 1.0f);
        }
    }
}

extern "C" void kernel_launch(void* const* d_in, const int* in_sizes, int n_in,
                              void* d_out, int out_size, void* d_ws, size_t ws_size,
                              hipStream_t stream) {
    const int* hashes = (const int*)d_in[0];
    float* out = (float*)d_out;

    // 1) zero-fill: 167,772,160 floats = 41,943,040 16B stores.
    const int n4 = OUT_ELEMS / 4;
    zero_out_kernel<<<8192, 256, 0, stream>>>((fx4*)out, n4);

    // 2) scatter: one thread per hash (65,536 threads).
    const int total_hashes = B_DIM * S_DIM * N_HASH;
    scatter_kernel<<<(total_hashes + 255) / 256, 256, 0, stream>>>(hashes, out);
}

// Round 4
// 655.999 us; speedup vs baseline: 1.1255x; 1.0766x over previous
//
#include <hip/hip_runtime.h>
#include <stdint.h>

// Problem constants (must match reference)
#define B_DIM 16
#define S_DIM 512
#define N_HASH 8
#define M_BLOOM 4096
#define W_WIN 2
#define K_BLOCKS (2 * W_WIN + 1)                       // 5
#define OUT_ELEMS (B_DIM * K_BLOCKS * M_BLOOM * S_DIM) // 167,772,160 floats

// Per-block slab: 64 m-rows of one batch, all 5 shift-blocks.
#define M_CHUNK 64
#define TILE_STRIDE 520                 // 4B guard + 512 data + 4B guard
#define TILE_BYTES (M_CHUNK * TILE_STRIDE)  // 33,280 B -> 4 blocks/CU

typedef float fx4 __attribute__((ext_vector_type(4)));

// One kernel, write-once, no global atomics.
//   out[b, k*M + m, s] = #{n : hashes[b, s + k - W, n] % M == m}, 0 if s+k-W OOB.
// Block = (b, m-chunk of 64). LDS holds uint8 counts tile[m][s] with 4-byte
// zero guards each side so the +/-2 shifted reads in phase 3 need no bounds
// checks (OOB s_in lands in a zeroed guard byte).
__global__ __launch_bounds__(256) void bloom_window_kernel(
    const int* __restrict__ hashes, float* __restrict__ out) {
    __shared__ uint32_t tile32[TILE_BYTES / 4];
    uint8_t* tile = (uint8_t*)tile32;

    const int tid = threadIdx.x;
    const int b = blockIdx.x >> 6;          // 64 chunks per batch
    const int chunk = blockIdx.x & 63;
    const int m0 = chunk * M_CHUNK;

    // Phase 1: zero the tile (incl. guards). 8320 words / 256 thr = 33 ea.
    for (int i = tid; i < TILE_BYTES / 4; i += 256) tile32[i] = 0;
    __syncthreads();

    // Phase 2: histogram. Thread owns s-columns {2*tid, 2*tid+1} -> no LDS
    // write collisions (DS has native byte enables; different bytes of one
    // word from different lanes are safe).
    const int4* hp = (const int4*)hashes;
#pragma unroll
    for (int ss = 0; ss < 2; ++ss) {
        const int s = 2 * tid + ss;
        const int4 h01 = hp[(b * S_DIM + s) * 2 + 0];
        const int4 h23 = hp[(b * S_DIM + s) * 2 + 1];
        const int hv[8] = {h01.x, h01.y, h01.z, h01.w,
                           h23.x, h23.y, h23.z, h23.w};
#pragma unroll
        for (int n = 0; n < N_HASH; ++n) {
            const int m = hv[n] & (M_BLOOM - 1);
            const unsigned ml = (unsigned)(m - m0);
            if (ml < M_CHUNK) {
                tile[ml * TILE_STRIDE + 4 + s] += 1;
            }
        }
    }
    __syncthreads();

    // Phase 3: stream out 5 shifted copies, write-once, coalesced float4.
    // rows r = k*64 + m (320 rows x 128 float4). value = tile[m][s + k - 2].
    fx4* out4 = (fx4*)out;
    const int n_items = K_BLOCKS * M_CHUNK * (S_DIM / 4);  // 40,960
    for (int idx = tid; idx < n_items; idx += 256) {
        const int j = idx & 127;        // float4 index along s
        const int r = idx >> 7;
        const int k = r >> 6;
        const int m = r & 63;

        // byte base of the 4 needed counts (may be unaligned by k-2)
        const int base = m * TILE_STRIDE + 4 + 4 * j + (k - 2);
        const uint32_t* wp = (const uint32_t*)(tile + (base & ~3));
        const uint32_t lo = wp[0];
        const uint32_t hi = wp[1];
        const uint32_t sh = (uint32_t)(base & 3) * 8u;
        const uint32_t packed = sh ? ((lo >> sh) | (hi << (32u - sh))) : lo;

        fx4 v;
        v.x = (float)(packed & 0xffu);
        v.y = (float)((packed >> 8) & 0xffu);
        v.z = (float)((packed >> 16) & 0xffu);
        v.w = (float)((packed >> 24) & 0xffu);

        // out row = (b*5 + k)*M + m0 + m; 128 float4 per row
        const int row = (b * K_BLOCKS + k) * M_BLOOM + m0 + m;
        out4[(long long)row * (S_DIM / 4) + j] = v;
    }
}

extern "C" void kernel_launch(void* const* d_in, const int* in_sizes, int n_in,
                              void* d_out, int out_size, void* d_ws, size_t ws_size,
                              hipStream_t stream) {
    const int* hashes = (const int*)d_in[0];
    float* out = (float*)d_out;

    // 16 batches x 64 m-chunks = 1024 blocks; 33 KB LDS -> 4 blocks/CU.
    bloom_window_kernel<<<B_DIM * (M_BLOOM / M_CHUNK), 256, 0, stream>>>(hashes, out);
}